// Round 1
// baseline (569.820 us; speedup 1.0000x reference)
//
#include <hip/hip_runtime.h>

// Problem constants (match reference): B=256, T=2048, D_IN=64, D_H=64, D_OUT=1
#define TSEQ  2048
#define DH    64
#define DIN   64
#define CHUNK 64
#define NPROD 2   // producer waves

// One block per batch element. Wave 0: serial recurrence (latency-critical).
// Waves 1..NPROD: precompute a[t,:] = W_xh @ x[t,:] into LDS double buffer.
__global__ __launch_bounds__(64 * (NPROD + 1))
void rnn_kernel(const float* __restrict__ x,
                const int*   __restrict__ seq_lengths,
                const float* __restrict__ W_xh,
                const float* __restrict__ W_hh,
                const float* __restrict__ W_out,
                const float* __restrict__ b_out,
                float*       __restrict__ out)
{
    const int b    = blockIdx.x;
    const int wave = threadIdx.x >> 6;
    const int lane = threadIdx.x & 63;
    const int L    = seq_lengths[b];

    __shared__ float a_buf[2][CHUNK][DH];

    const float* __restrict__ xb = x + (size_t)b * TSEQ * DIN;

    // Per-lane weight row in registers (64 VGPRs).
    float w[DH];
    if (wave == 0) {
        #pragma unroll
        for (int k = 0; k < DH; ++k) w[k] = W_hh[lane * DH + k];
    } else {
        #pragma unroll
        for (int i = 0; i < DIN; ++i) w[i] = W_xh[lane * DIN + i];
    }

    float h = 0.0f;
    const int nchunks = (L + CHUNK - 1) / CHUNK;

    // Pipelined chunks: iteration c -> producers fill chunk c, consumer eats chunk c-1.
    for (int c = 0; c < nchunks + 1; ++c) {
        if (wave > 0 && c < nchunks) {
            const int base = c * CHUNK;
            const int cnt  = min(CHUNK, L - base);
            for (int tt = wave - 1; tt < cnt; tt += NPROD) {
                const float* xt = xb + (size_t)(base + tt) * DIN;
                float a0 = 0.f, a1 = 0.f, a2 = 0.f, a3 = 0.f;
                #pragma unroll
                for (int i = 0; i < DIN; i += 4) {
                    a0 = fmaf(w[i + 0], xt[i + 0], a0);   // xt[i] is wave-uniform (broadcast)
                    a1 = fmaf(w[i + 1], xt[i + 1], a1);
                    a2 = fmaf(w[i + 2], xt[i + 2], a2);
                    a3 = fmaf(w[i + 3], xt[i + 3], a3);
                }
                a_buf[c & 1][tt][lane] = (a0 + a1) + (a2 + a3);
            }
        }
        if (wave == 0 && c > 0) {
            const int base = (c - 1) * CHUNK;
            const int cnt  = min(CHUNK, L - base);
            const int buf  = (c - 1) & 1;
            for (int tt = 0; tt < cnt; ++tt) {
                const float aval = a_buf[buf][tt][lane];
                float z0 = 0.f, z1 = 0.f, z2 = 0.f, z3 = 0.f;
                #pragma unroll
                for (int k = 0; k < DH; k += 4) {
                    // Broadcast h[k] (lane k's register) to an SGPR; folds into v_fma as scalar src.
                    const float h0 = __int_as_float(__builtin_amdgcn_readlane(__float_as_int(h), k + 0));
                    const float h1 = __int_as_float(__builtin_amdgcn_readlane(__float_as_int(h), k + 1));
                    const float h2 = __int_as_float(__builtin_amdgcn_readlane(__float_as_int(h), k + 2));
                    const float h3 = __int_as_float(__builtin_amdgcn_readlane(__float_as_int(h), k + 3));
                    z0 = fmaf(w[k + 0], h0, z0);
                    z1 = fmaf(w[k + 1], h1, z1);
                    z2 = fmaf(w[k + 2], h2, z2);
                    z3 = fmaf(w[k + 3], h3, z3);
                }
                float z = ((z0 + z1) + (z2 + z3)) + aval;
                // tanh(z) = 1 - 2/(exp(2z)+1); clamp to keep exp finite.
                z = fminf(fmaxf(z, -15.0f), 15.0f);
                const float e2 = __expf(2.0f * z);
                h = fmaf(-2.0f, __builtin_amdgcn_rcpf(e2 + 1.0f), 1.0f);
            }
        }
        __syncthreads();
    }

    if (wave == 0) {
        // out[b] = dot(h, W_out[0,:]) + b_out[0]
        float o = h * W_out[lane];
        #pragma unroll
        for (int off = 32; off > 0; off >>= 1)
            o += __shfl_xor(o, off, 64);
        if (lane == 0) out[b] = o + b_out[0];
    }
}

extern "C" void kernel_launch(void* const* d_in, const int* in_sizes, int n_in,
                              void* d_out, int out_size, void* d_ws, size_t ws_size,
                              hipStream_t stream) {
    const float* x     = (const float*)d_in[0];
    const int*   slen  = (const int*)  d_in[1];
    const float* W_xh  = (const float*)d_in[2];
    const float* W_hh  = (const float*)d_in[3];
    const float* W_out = (const float*)d_in[4];
    const float* b_out = (const float*)d_in[5];
    float* out = (float*)d_out;

    const int B = in_sizes[1];  // 256
    rnn_kernel<<<dim3(B), dim3(64 * (NPROD + 1)), 0, stream>>>(
        x, slen, W_xh, W_hh, W_out, b_out, out);
}